// Round 11
// baseline (698.257 us; speedup 1.0000x reference)
//
#include <hip/hip_runtime.h>
#include <hip/hip_fp16.h>

#define BSZ 1024   // B
#define VSZ 4096   // V
#define NBLK 32    // sinkhorn blocks (32 j-rows each, 512 threads)
#define JPB 32     // j's per sinkhorn block
#define KPAD 1040  // LDS row stride for K (1024 + 16 floats)

typedef _Float16 h2 __attribute__((ext_vector_type(2)));
union F4H { float4 f; h2 h[4]; };

#if defined(__has_builtin) && __has_builtin(__builtin_elementwise_min)
#define H2MIN(a, b) __builtin_elementwise_min((a), (b))
#else
static __device__ inline h2 H2MIN(h2 a, h2 b) {
    h2 r; r[0] = a[0] < b[0] ? a[0] : b[0]; r[1] = a[1] < b[1] ? a[1] : b[1]; return r;
}
#endif

// packed f16 dot-accumulate: acc += m[0] + m[1]  (v_dot2_f32_f16)
static __device__ inline float dot2acc(h2 m, float acc) {
#if defined(__has_builtin) && __has_builtin(__builtin_amdgcn_fdot2)
    const h2 ones = {(_Float16)1.0f, (_Float16)1.0f};
    return __builtin_amdgcn_fdot2(m, ones, acc, false);
#else
    return acc + (float)m[0] + (float)m[1];
#endif
}

// ---------------- softmax(y/2) row-wise, writes f16 probs ---------------------
__global__ __launch_bounds__(256) void softmax_kernel(const float* __restrict__ ys,
                                                      const float* __restrict__ yt,
                                                      __half* __restrict__ ps,
                                                      __half* __restrict__ pt) {
    int row = blockIdx.x;
    const float* src;
    __half* dst;
    if (row < BSZ) { src = ys + (size_t)row * VSZ;         dst = ps + (size_t)row * VSZ; }
    else           { src = yt + (size_t)(row - BSZ) * VSZ; dst = pt + (size_t)(row - BSZ) * VSZ; }
    int t = threadIdx.x;
    float4 v[4];
    float m = -1e30f;
#pragma unroll
    for (int k = 0; k < 4; ++k) {
        v[k] = ((const float4*)src)[t + 256 * k];
        m = fmaxf(m, fmaxf(fmaxf(v[k].x, v[k].y), fmaxf(v[k].z, v[k].w)));
    }
#pragma unroll
    for (int d = 32; d >= 1; d >>= 1) m = fmaxf(m, __shfl_down(m, d));
    __shared__ float sred[4];
    __shared__ float sred2[4];
    int lane = t & 63, wid = t >> 6;
    if (lane == 0) sred[wid] = m;
    __syncthreads();
    m = fmaxf(fmaxf(sred[0], sred[1]), fmaxf(sred[2], sred[3]));
    const float C = 0.7213475204444817f;  // 0.5 * log2(e)  (T = 2)
    float s = 0.f;
#pragma unroll
    for (int k = 0; k < 4; ++k) {
        v[k].x = exp2f((v[k].x - m) * C);
        v[k].y = exp2f((v[k].y - m) * C);
        v[k].z = exp2f((v[k].z - m) * C);
        v[k].w = exp2f((v[k].w - m) * C);
        s += (v[k].x + v[k].y) + (v[k].z + v[k].w);
    }
#pragma unroll
    for (int d = 32; d >= 1; d >>= 1) s += __shfl_down(s, d);
    if (lane == 0) sred2[wid] = s;
    __syncthreads();
    s = (sred2[0] + sred2[1]) + (sred2[2] + sred2[3]);
    float inv = 1.0f / s;
#pragma unroll
    for (int k = 0; k < 4; ++k) {
        union { __half h[4]; uint2 u; } o;
        o.h[0] = __float2half(v[k].x * inv);
        o.h[1] = __float2half(v[k].y * inv);
        o.h[2] = __float2half(v[k].z * inv);
        o.h[3] = __float2half(v[k].w * inv);
        ((uint2*)dst)[t + 256 * k] = o.u;
    }
}

// ---------------- S-partial: ST[j][i] = sum_v min(ps[i,v], pt[j,v])  ----------
// 128x128 tile, 8x8 per thread: 16 ds_read_b128 serve 64 combos (2x reuse of
// R5's 4x4). NO VGPR cap (R1/R7 law: capping this kernel -> multi-GB spill).
#define TI 128
#define LSTRH 72  // f16 row stride (144 B): 2-way bank aliasing -> free (m136)

__global__ __launch_bounds__(256) void cdist_kernel(const __half* __restrict__ psh,
                                                    const __half* __restrict__ pth,
                                                    float* __restrict__ spart) {
    __shared__ __half sP[2][TI * LSTRH];   // 18,432 B per buf
    __shared__ __half sQ[2][TI * LSTRH];   // total 73,728 B
    const int bi = blockIdx.x;
    const int bj = blockIdx.y;
    const int bv = blockIdx.z;
    const int t = threadIdx.x;
    const int cl = t & 15;   // i-lane
    const int rl = t >> 4;   // j-lane
    const __half* psb = psh + ((size_t)bi * TI) * VSZ + bv * 1024;
    const __half* ptb = pth + ((size_t)bj * TI) * VSZ + bv * 1024;
    // staging: each thread owns 64 contiguous bytes (4 f4) of one row-half,
    // for BOTH P and Q: row = t>>1 (0..127), half = (t&1)*32. (R5-verified map.)
    const int srow = t >> 1;
    const int sc0 = (t & 1) * 32;
    const __half* gp = psb + (size_t)srow * VSZ + sc0;
    const __half* gq = ptb + (size_t)srow * VSZ + sc0;
    __half* lp0 = &sP[0][srow * LSTRH + sc0];
    __half* lp1 = &sP[1][srow * LSTRH + sc0];
    __half* lq0 = &sQ[0][srow * LSTRH + sc0];
    __half* lq1 = &sQ[1][srow * LSTRH + sc0];

    float acc[8][8] = {};

    {   // prologue: stage tile 0 into buf 0
#pragma unroll
        for (int k = 0; k < 4; ++k) *(float4*)(lp0 + 8 * k) = *(const float4*)(gp + 8 * k);
#pragma unroll
        for (int k = 0; k < 4; ++k) *(float4*)(lq0 + 8 * k) = *(const float4*)(gq + 8 * k);
    }
    __syncthreads();

    for (int kt = 0; kt < 16; ++kt) {
        const int cur = kt & 1;
        float4 rp[4], rq[4];
        if (kt < 15) {
            const __half* p = gp + (kt + 1) * 64;
            const __half* q = gq + (kt + 1) * 64;
#pragma unroll
            for (int k = 0; k < 4; ++k) rp[k] = *(const float4*)(p + 8 * k);
#pragma unroll
            for (int k = 0; k < 4; ++k) rq[k] = *(const float4*)(q + 8 * k);
        }
        const __half* pbase = sP[cur] + cl * LSTRH;
        const __half* qbase = sQ[cur] + rl * LSTRH;
#pragma unroll
        for (int vv = 0; vv < 8; ++vv) {
            F4H p[8], q[8];
#pragma unroll
            for (int u = 0; u < 8; ++u)
                p[u].f = *(const float4*)(pbase + u * 16 * LSTRH + vv * 8);
#pragma unroll
            for (int w = 0; w < 8; ++w)
                q[w].f = *(const float4*)(qbase + w * 16 * LSTRH + vv * 8);
#pragma unroll
            for (int u = 0; u < 8; ++u)
#pragma unroll
                for (int w = 0; w < 8; ++w) {
                    float a = acc[u][w];
                    a = dot2acc(H2MIN(p[u].h[0], q[w].h[0]), a);
                    a = dot2acc(H2MIN(p[u].h[1], q[w].h[1]), a);
                    a = dot2acc(H2MIN(p[u].h[2], q[w].h[2]), a);
                    a = dot2acc(H2MIN(p[u].h[3], q[w].h[3]), a);
                    acc[u][w] = a;
                }
        }
        if (kt < 15) {
            __half* lp = cur ? lp0 : lp1;
            __half* lq = cur ? lq0 : lq1;
#pragma unroll
            for (int k = 0; k < 4; ++k) *(float4*)(lp + 8 * k) = rp[k];
#pragma unroll
            for (int k = 0; k < 4; ++k) *(float4*)(lq + 8 * k) = rq[k];
        }
        __syncthreads();
    }

    float* outp = spart + (size_t)bv * (BSZ * BSZ);
#pragma unroll
    for (int w = 0; w < 8; ++w) {
        int jr = bj * TI + rl + 16 * w;
#pragma unroll
        for (int u = 0; u < 8; ++u) {
            int ic = bi * TI + cl + 16 * u;
            outp[(size_t)jr * BSZ + ic] = acc[u][w];
        }
    }
}

// ------- combine v-partials: W = 2 - 2*S, K = exp(-W/eps); init barrier flags -
__global__ __launch_bounds__(256) void combine_kernel(const float* __restrict__ spart,
                                                      float* __restrict__ wt,
                                                      float* __restrict__ kt,
                                                      unsigned* __restrict__ flags) {
    if (blockIdx.x == 0 && threadIdx.x < NBLK) flags[threadIdx.x * 32] = 0u;
    int idx = blockIdx.x * 256 + threadIdx.x;  // over B*B/4 float4s
    const float4* p0 = (const float4*)spart;
    const int Q = (BSZ * BSZ) / 4;
    float4 a = p0[idx], b = p0[idx + Q], c = p0[idx + 2 * Q], d = p0[idx + 3 * Q];
    float4 w;
    w.x = 2.0f - 2.0f * ((a.x + b.x) + (c.x + d.x));
    w.y = 2.0f - 2.0f * ((a.y + b.y) + (c.y + d.y));
    w.z = 2.0f - 2.0f * ((a.z + b.z) + (c.z + d.z));
    w.w = 2.0f - 2.0f * ((a.w + b.w) + (c.w + d.w));
    ((float4*)wt)[idx] = w;
    const float CE = -14.426950408889634f;  // -log2(e)/eps, eps=0.1
    float4 k;
    k.x = exp2f(w.x * CE);
    k.y = exp2f(w.y * CE);
    k.z = exp2f(w.z * CE);
    k.w = exp2f(w.w * CE);
    ((float4*)kt)[idx] = k;
}

// ------- grid barrier v4: all-to-all (no master/go relay hop) -----------------
__device__ inline void grid_barrier(unsigned* flags, unsigned gen) {
    __syncthreads();
    const int t = threadIdx.x;
    if (t == 0)  // RELEASE: flush this block's cpart/outpart stores
        __hip_atomic_store(&flags[blockIdx.x * 32], gen, __ATOMIC_RELEASE, __HIP_MEMORY_SCOPE_AGENT);
    if (t < NBLK) {
        while (__hip_atomic_load(&flags[t * 32], __ATOMIC_RELAXED, __HIP_MEMORY_SCOPE_AGENT) < gen)
            __builtin_amdgcn_s_sleep(1);
    }
    __syncthreads();
    if (t == 0)  // single ACQUIRE: one L1/L2 inv for the whole block
        (void)__hip_atomic_load(&flags[0], __ATOMIC_ACQUIRE, __HIP_MEMORY_SCOPE_AGENT);
    __syncthreads();
}

// ---------------- Sinkhorn: a = 1/(K b); b = 1/(K^T a), 20 iters + final sum --
__global__ __launch_bounds__(512) void sinkhorn_kernel(const float* __restrict__ KT,
                                                       const float* __restrict__ WT,
                                                       float* __restrict__ cpart,
                                                       float* __restrict__ outpart,
                                                       float* __restrict__ out,
                                                       unsigned* __restrict__ flags) {
    __shared__ __align__(16) float k_lds[JPB * KPAD];   // 133,120 B
    __shared__ __align__(16) float a_sh[BSZ];
    __shared__ float b_sh[JPB];
    __shared__ float red[JPB];
    const int z = blockIdx.x;
    const int t = threadIdx.x;
    const int j0 = z * JPB;
#pragma unroll
    for (int m = 0; m < 16; ++m) {
        int idx = t + 512 * m;
        int row = idx >> 8;
        int col = (idx & 255) * 4;
        float4 v = *(const float4*)(KT + (size_t)(j0 + row) * BSZ + col);
        *(float4*)(&k_lds[row * KPAD + col]) = v;
    }
    if (t < JPB) b_sh[t] = 1.0f;
    __syncthreads();
    const int jj = t >> 4;   // 0..31
    const int il = t & 15;
    unsigned gen = 1u;
    for (int it = 0; it < 20; ++it) {
        float* cur = cpart + (size_t)(it & 1) * (NBLK * BSZ) + (size_t)z * BSZ;
        float2 s = {0.f, 0.f};
#pragma unroll
        for (int q = 0; q < JPB; ++q) {
            float2 kv = *(const float2*)(&k_lds[q * KPAD + 2 * t]);
            float bb = b_sh[q];
            s.x += kv.x * bb; s.y += kv.y * bb;
        }
        ((float2*)cur)[t] = s;
        grid_barrier(flags, gen++);
        const float* curAll = cpart + (size_t)(it & 1) * (NBLK * BSZ);
        float2 c = {0.f, 0.f};
#pragma unroll 8
        for (int zz = 0; zz < NBLK; ++zz) {
            float2 v = ((const float2*)curAll)[zz * 512 + t];
            c.x += v.x; c.y += v.y;
        }
        float2 ar;
        ar.x = 1.0f / c.x; ar.y = 1.0f / c.y;
        ((float2*)a_sh)[t] = ar;
        __syncthreads();
        float sb = 0.f;
#pragma unroll
        for (int m2 = 0; m2 < 16; ++m2) {
            float4 kv = *(const float4*)(&k_lds[jj * KPAD + (il + 16 * m2) * 4]);
            float4 av = ((const float4*)a_sh)[il + 16 * m2];
            sb += (kv.x * av.x + kv.y * av.y) + (kv.z * av.z + kv.w * av.w);
        }
#pragma unroll
        for (int d = 8; d >= 1; d >>= 1) sb += __shfl_down(sb, d, 16);
        if (il == 0) b_sh[jj] = 1.0f / sb;
        __syncthreads();
    }
    {
        const float4* wrow = (const float4*)(WT + (size_t)(j0 + jj) * BSZ);
        float sb = 0.f;
#pragma unroll 4
        for (int m2 = 0; m2 < 16; ++m2) {
            float4 kv = *(const float4*)(&k_lds[jj * KPAD + (il + 16 * m2) * 4]);
            float4 wv = wrow[il + 16 * m2];
            float4 av = ((const float4*)a_sh)[il + 16 * m2];
            sb += (av.x * kv.x * wv.x + av.y * kv.y * wv.y) +
                  (av.z * kv.z * wv.z + av.w * kv.w * wv.w);
        }
#pragma unroll
        for (int d = 8; d >= 1; d >>= 1) sb += __shfl_down(sb, d, 16);
        if (il == 0) red[jj] = sb * b_sh[jj];
        __syncthreads();
        if (t == 0) {
            float ss = 0.f;
#pragma unroll
            for (int q = 0; q < JPB; ++q) ss += red[q];
            outpart[z] = ss;
        }
    }
    grid_barrier(flags, gen++);
    if (z == 0 && t == 0) {
        float ss = 0.f;
        for (int q = 0; q < NBLK; ++q) ss += outpart[q];
        out[0] = 0.001f * ss;
    }
}

extern "C" void kernel_launch(void* const* d_in, const int* in_sizes, int n_in,
                              void* d_out, int out_size, void* d_ws, size_t ws_size,
                              hipStream_t stream) {
    const float* ys = (const float*)d_in[0];
    const float* yt = (const float*)d_in[1];
    float* ws = (float*)d_ws;
    __half* psh    = (__half*)ws;                          // 2M floats
    __half* pth    = (__half*)(ws + 2ull * 1024 * 1024);   // 2M floats
    float* spart   = ws + 4ull * 1024 * 1024;              // 4 x 1M
    float* wt      = spart + 4ull * BSZ * BSZ;             // 1M
    float* kt      = wt + (size_t)BSZ * BSZ;               // 1M
    float* cpart   = kt + (size_t)BSZ * BSZ;               // 2*32*1024
    float* outpart = cpart + 2ull * NBLK * BSZ;            // 32 (+pad)
    unsigned* flags = (unsigned*)(outpart + 128);          // NBLK x 32 uints (128B stride)
    float* outp    = (float*)d_out;

    softmax_kernel<<<dim3(2 * BSZ), dim3(256), 0, stream>>>(ys, yt, psh, pth);
    cdist_kernel<<<dim3(8, 8, 4), dim3(256), 0, stream>>>(psh, pth, spart);
    combine_kernel<<<dim3((BSZ * BSZ / 4) / 256), dim3(256), 0, stream>>>(spart, wt, kt, flags);

    void* args[] = {(void*)&kt, (void*)&wt, (void*)&cpart, (void*)&outpart, (void*)&outp,
                    (void*)&flags};
    (void)hipLaunchCooperativeKernel((void*)sinkhorn_kernel, dim3(NBLK), dim3(512), args, 0, stream);
}